// Round 1
// baseline (291.618 us; speedup 1.0000x reference)
//
#include <hip/hip_runtime.h>

#define D_ 160
#define H_ 192
#define W_ 160
// C = 4 floats = one float4 per voxel.

__global__ __launch_bounds__(256) void st_trilinear_kernel(
    const float4* __restrict__ vol,   // [D,H,W] of float4
    const float*  __restrict__ df,    // [D,H,W,3]
    float4*       __restrict__ out)   // [D,H,W] of float4
{
    int idx = blockIdx.x * blockDim.x + threadIdx.x;
    constexpr int NV = D_ * H_ * W_;
    if (idx >= NV) return;

    int x = idx % W_;
    int t = idx / W_;
    int y = t % H_;
    int z = t / H_;

    // df layout interleaved: [z,y,x,3] -> (dz, dy, dx) matching dims (D,H,W)
    float dz = df[3 * idx + 0];
    float dy = df[3 * idx + 1];
    float dx = df[3 * idx + 2];

    float lz = (float)z + dz;
    float ly = (float)y + dy;
    float lx = (float)x + dx;

    // Reference semantics: loc0c = clip(floor(loc), 0, max); loc1 = clip(loc0c+1, 0, max)
    float z0f = fminf(fmaxf(floorf(lz), 0.f), (float)(D_ - 1));
    float y0f = fminf(fmaxf(floorf(ly), 0.f), (float)(H_ - 1));
    float x0f = fminf(fmaxf(floorf(lx), 0.f), (float)(W_ - 1));
    float z1f = fminf(z0f + 1.f, (float)(D_ - 1));   // z0f >= 0 so lower clip is a no-op
    float y1f = fminf(y0f + 1.f, (float)(H_ - 1));
    float x1f = fminf(x0f + 1.f, (float)(W_ - 1));

    // weights[0] (corner 0) = loc1 - loc ; weights[1] (corner 1) = 1 - (loc1 - loc)
    float wz0 = z1f - lz, wz1 = 1.f - wz0;
    float wy0 = y1f - ly, wy1 = 1.f - wy0;
    float wx0 = x1f - lx, wx1 = 1.f - wx0;

    int iz0 = (int)z0f, iz1 = (int)z1f;
    int iy0 = (int)y0f, iy1 = (int)y1f;
    int ix0 = (int)x0f, ix1 = (int)x1f;

    int b00 = (iz0 * H_ + iy0) * W_;
    int b01 = (iz0 * H_ + iy1) * W_;
    int b10 = (iz1 * H_ + iy0) * W_;
    int b11 = (iz1 * H_ + iy1) * W_;

    float4 v000 = vol[b00 + ix0];
    float4 v001 = vol[b00 + ix1];
    float4 v010 = vol[b01 + ix0];
    float4 v011 = vol[b01 + ix1];
    float4 v100 = vol[b10 + ix0];
    float4 v101 = vol[b10 + ix1];
    float4 v110 = vol[b11 + ix0];
    float4 v111 = vol[b11 + ix1];

    float w000 = wz0 * wy0 * wx0;
    float w001 = wz0 * wy0 * wx1;
    float w010 = wz0 * wy1 * wx0;
    float w011 = wz0 * wy1 * wx1;
    float w100 = wz1 * wy0 * wx0;
    float w101 = wz1 * wy0 * wx1;
    float w110 = wz1 * wy1 * wx0;
    float w111 = wz1 * wy1 * wx1;

    float4 r;
    r.x = w000 * v000.x + w001 * v001.x + w010 * v010.x + w011 * v011.x
        + w100 * v100.x + w101 * v101.x + w110 * v110.x + w111 * v111.x;
    r.y = w000 * v000.y + w001 * v001.y + w010 * v010.y + w011 * v011.y
        + w100 * v100.y + w101 * v101.y + w110 * v110.y + w111 * v111.y;
    r.z = w000 * v000.z + w001 * v001.z + w010 * v010.z + w011 * v011.z
        + w100 * v100.z + w101 * v101.z + w110 * v110.z + w111 * v111.z;
    r.w = w000 * v000.w + w001 * v001.w + w010 * v010.w + w011 * v011.w
        + w100 * v100.w + w101 * v101.w + w110 * v110.w + w111 * v111.w;

    out[idx] = r;
}

extern "C" void kernel_launch(void* const* d_in, const int* in_sizes, int n_in,
                              void* d_out, int out_size, void* d_ws, size_t ws_size,
                              hipStream_t stream) {
    const float4* vol = (const float4*)d_in[0];  // (160,192,160,4) f32
    const float*  df  = (const float*)d_in[1];   // (160,192,160,3) f32
    float4* out = (float4*)d_out;                // (160,192,160,4) f32

    constexpr int NV = D_ * H_ * W_;
    int block = 256;
    int grid = (NV + block - 1) / block;
    st_trilinear_kernel<<<grid, block, 0, stream>>>(vol, df, out);
}

// Round 2
// 231.016 us; speedup vs baseline: 1.2623x; 1.2623x over previous
//
#include <hip/hip_runtime.h>

#define D_ 160
#define H_ 192
#define W_ 160
// Tile: 16 (x) x 4 (y) x 4 (z) = 256 threads. Wave = one z-plane of 16x4.
// Rationale: block corner-gather footprint ~23 KB fits 32 KB L1, converting
// per-lane gather transactions from L1 misses (miss-queue bound ~0.3/cyc) to
// L1 hits (~1/cyc TA throughput).

__global__ __launch_bounds__(256) void st_trilinear_kernel(
    const float4* __restrict__ vol,   // [D,H,W] of float4
    const float*  __restrict__ df,    // [D,H,W,3]
    float4*       __restrict__ out)   // [D,H,W] of float4
{
    int tid = threadIdx.x;
    int x = blockIdx.x * 16 + (tid & 15);
    int y = blockIdx.y * 4  + ((tid >> 4) & 3);
    int z = blockIdx.z * 4  + (tid >> 6);

    int idx = (z * H_ + y) * W_ + x;

    float dz = df[3 * idx + 0];
    float dy = df[3 * idx + 1];
    float dx = df[3 * idx + 2];

    float lz = (float)z + dz;
    float ly = (float)y + dy;
    float lx = (float)x + dx;

    // Reference semantics: loc0c = clip(floor(loc), 0, max); loc1 = clip(loc0c+1, 0, max)
    float z0f = fminf(fmaxf(floorf(lz), 0.f), (float)(D_ - 1));
    float y0f = fminf(fmaxf(floorf(ly), 0.f), (float)(H_ - 1));
    float x0f = fminf(fmaxf(floorf(lx), 0.f), (float)(W_ - 1));
    float z1f = fminf(z0f + 1.f, (float)(D_ - 1));
    float y1f = fminf(y0f + 1.f, (float)(H_ - 1));
    float x1f = fminf(x0f + 1.f, (float)(W_ - 1));

    // weights[0] (corner 0) = loc1 - loc ; weights[1] (corner 1) = 1 - (loc1 - loc)
    float wz0 = z1f - lz, wz1 = 1.f - wz0;
    float wy0 = y1f - ly, wy1 = 1.f - wy0;
    float wx0 = x1f - lx, wx1 = 1.f - wx0;

    int iz0 = (int)z0f, iz1 = (int)z1f;
    int iy0 = (int)y0f, iy1 = (int)y1f;
    int ix0 = (int)x0f, ix1 = (int)x1f;

    int b00 = (iz0 * H_ + iy0) * W_;
    int b01 = (iz0 * H_ + iy1) * W_;
    int b10 = (iz1 * H_ + iy0) * W_;
    int b11 = (iz1 * H_ + iy1) * W_;

    float4 v000 = vol[b00 + ix0];
    float4 v001 = vol[b00 + ix1];
    float4 v010 = vol[b01 + ix0];
    float4 v011 = vol[b01 + ix1];
    float4 v100 = vol[b10 + ix0];
    float4 v101 = vol[b10 + ix1];
    float4 v110 = vol[b11 + ix0];
    float4 v111 = vol[b11 + ix1];

    float w000 = wz0 * wy0 * wx0;
    float w001 = wz0 * wy0 * wx1;
    float w010 = wz0 * wy1 * wx0;
    float w011 = wz0 * wy1 * wx1;
    float w100 = wz1 * wy0 * wx0;
    float w101 = wz1 * wy0 * wx1;
    float w110 = wz1 * wy1 * wx0;
    float w111 = wz1 * wy1 * wx1;

    float4 r;
    r.x = w000 * v000.x + w001 * v001.x + w010 * v010.x + w011 * v011.x
        + w100 * v100.x + w101 * v101.x + w110 * v110.x + w111 * v111.x;
    r.y = w000 * v000.y + w001 * v001.y + w010 * v010.y + w011 * v011.y
        + w100 * v100.y + w101 * v101.y + w110 * v110.y + w111 * v111.y;
    r.z = w000 * v000.z + w001 * v001.z + w010 * v010.z + w011 * v011.z
        + w100 * v100.z + w101 * v101.z + w110 * v110.z + w111 * v111.z;
    r.w = w000 * v000.w + w001 * v001.w + w010 * v010.w + w011 * v011.w
        + w100 * v100.w + w101 * v101.w + w110 * v110.w + w111 * v111.w;

    out[idx] = r;
}

extern "C" void kernel_launch(void* const* d_in, const int* in_sizes, int n_in,
                              void* d_out, int out_size, void* d_ws, size_t ws_size,
                              hipStream_t stream) {
    const float4* vol = (const float4*)d_in[0];  // (160,192,160,4) f32
    const float*  df  = (const float*)d_in[1];   // (160,192,160,3) f32
    float4* out = (float4*)d_out;                // (160,192,160,4) f32

    dim3 grid(W_ / 16, H_ / 4, D_ / 4);  // 10 x 48 x 40
    st_trilinear_kernel<<<grid, 256, 0, stream>>>(vol, df, out);
}